// Round 11
// baseline (229.747 us; speedup 1.0000x reference)
//
#include <hip/hip_runtime.h>

// ---------- types ----------
typedef _Float16 h16;
typedef _Float16 h16x8 __attribute__((ext_vector_type(8)));
typedef _Float16 h16x4 __attribute__((ext_vector_type(4)));
typedef float    f32x4 __attribute__((ext_vector_type(4)));

#define NBATCH 16
#define LROWS  1024
#define FDIM   256

// d_out element offsets (fp32 elements)
#define OFF_TGT 0ull
#define OFF_CLM 1048576ull
#define OFF_NR  4194304ull     // + layer*4194304
#define OFF_AT  16777216ull    // + layer*16777216

__device__ __forceinline__ void split2(float x, h16& h, h16& l) {
    h = (h16)x;
    l = (h16)(x - (float)h);
}

// global_load_lds width-16 helper (dest = wave-uniform base + lane*16)
typedef const __attribute__((address_space(1))) void gvoid;
typedef __attribute__((address_space(3))) void lvoid;
__device__ __forceinline__ void gl_lds16(const void* g, void* l) {
    __builtin_amdgcn_global_load_lds((gvoid*)g, (lvoid*)l, 16, 0, 0);
}

// upper-triangle tile enumeration (36 pairs, it <= jt, 8x8 tiles)
__device__ const unsigned char TRI_I[36] = {
    0,0,0,0,0,0,0,0, 1,1,1,1,1,1,1, 2,2,2,2,2,2, 3,3,3,3,3, 4,4,4,4, 5,5,5, 6,6, 7};
__device__ const unsigned char TRI_J[36] = {
    0,1,2,3,4,5,6,7, 1,2,3,4,5,6,7, 2,3,4,5,6,7, 3,4,5,6,7, 4,5,6,7, 5,6,7, 6,7, 7};

// ---------- init: concat(target,claim) -> x hi/lo fp16 ; W -> hi fp16 ----------
// XCD-aligned: batch b's conversion runs on XCD b%8 (same as gemm_ct consumer).
__global__ __launch_bounds__(256) void convert_all(const float* __restrict__ tgt,
                                                   const float* __restrict__ clm,
                                                   const float* __restrict__ W,
                                                   h16* __restrict__ xh, h16* __restrict__ xl,
                                                   h16* __restrict__ wh) {
    int bid = blockIdx.x;
    if (bid < 4096) {
        int b, i;
        if (bid < 2048) { b = bid & 7;       i = bid >> 3; }
        else            { b = 8 + (bid & 7); i = (bid - 2048) >> 3; }
        size_t e = ((size_t)b << 18) + (size_t)i * 1024 + (size_t)threadIdx.x * 4;
        int rf = (int)(e & 262143);
        int r  = rf >> 8, f = rf & 255;
        const float* src = (r < 256)
            ? tgt + ((size_t)b << 16) + ((size_t)r << 8) + f
            : clm + (size_t)b * 196608 + ((size_t)(r - 256) << 8) + f;
        f32x4 v = *(const f32x4*)src;
        h16x4 hv, lv;
#pragma unroll
        for (int j = 0; j < 4; ++j) { h16 hh, ll; split2(v[j], hh, ll); hv[j] = hh; lv[j] = ll; }
        *(h16x4*)(xh + e) = hv;
        *(h16x4*)(xl + e) = lv;
    } else {
        size_t e = ((size_t)(bid - 4096) * 256 + threadIdx.x) * 4;
        f32x4 v = *(const f32x4*)(W + e);
        h16x4 hv;
#pragma unroll
        for (int j = 0; j < 4; ++j) hv[j] = (h16)v[j];
        *(h16x4*)(wh + e) = hv;
    }
}

// ---------- fused corr(symmetric)+trans, BK=32, double-buffered 64KB LDS, 2/CU ----------
// Batch-major-per-XCD grid: bid<416 -> b=bid&7, u=bid>>3; else b=8+((bid-416)&7),
// u=(bid-416)>>3. All 52 units of batch b run on XCD b%8, roughly one batch at a
// time per XCD -> 4MB working set fits the 4MB XCD L2.
// 2-phase pipeline: stage(kt+1, buf^1) issued BEFORE MFMA(buf); one barrier/kt.
// corr (u<36): 3-term split logits -> p_tilde fp16 (both orientations) + (max,sumexp)
//   partials (both orientations). trans (u>=36): 2-term (ah+al)·Wh -> tT fp16.
__global__ __launch_bounds__(256, 2) void gemm_ct(
    const h16* __restrict__ Xh, const h16* __restrict__ Xl,
    const h16* __restrict__ Wh,
    h16* __restrict__ Ptil, float2* __restrict__ part,
    h16* __restrict__ Th) {
    int b, u;
    if (blockIdx.x < 416) { b = blockIdx.x & 7;               u = blockIdx.x >> 3; }
    else                  { b = 8 + ((blockIdx.x - 416) & 7); u = (blockIdx.x - 416) >> 3; }
    const bool isCorr = u < 36;
    int it, jt;
    if (isCorr) { it = TRI_I[u]; jt = TRI_J[u]; }
    else        { int v = u - 36; it = v >> 1; jt = v & 1; }
    const int i0 = it * 128;
    const int j0 = jt * 128;
    const int t  = threadIdx.x;
    const int lane = t & 63, wid = t >> 6;
    const int wr = wid >> 1, wc = wid & 1;

    // two 32KB buffers; within each: Ah@0 | Al@8K | Bh@16K | Bl@24K, each [128][32]h16
    __shared__ alignas(16) char lds[65536];

    const size_t arow = ((size_t)b * LROWS + i0) * 256;
    const h16* bHp; const h16* bLp; size_t brow;
    if (isCorr) { bHp = Xh; bLp = Xl; brow = ((size_t)b * LROWS + j0) * 256; }
    else        { bHp = Wh; bLp = Xl; brow = (size_t)j0 * 256; }   // bLp unused for trans

    f32x4 acc[4][4];
#pragma unroll
    for (int i = 0; i < 4; ++i)
#pragma unroll
        for (int j = 0; j < 4; ++j) acc[i][j] = (f32x4){0.f, 0.f, 0.f, 0.f};

    const int grow = t >> 2;   // 0..63
    const int gq   = t & 3;    // 16B chunk within 64B row

    // stage(kt, base): issue async global->LDS for K-slice kt into buffer at `base`
    auto stage = [&](int kt, int base) {
#pragma unroll
        for (int p = 0; p < 2; ++p) {
            int r = p * 64 + grow;
            size_t so = (size_t)r * 256 + kt * 32 + ((gq ^ ((r >> 1) & 3)) << 3);
            char* d = lds + base + p * 4096 + wid * 1024;
            gl_lds16(Xh + arow + so, d);
            gl_lds16(Xl + arow + so, d + 8192);
            gl_lds16(bHp + brow + so, d + 16384);
            if (isCorr) gl_lds16(bLp + brow + so, d + 24576);
        }
    };

    stage(0, 0);
    __syncthreads();           // drain prologue stage

    for (int kt = 0; kt < 8; ++kt) {
        const int cb = (kt & 1) << 15;         // compute buffer base
        if (kt < 7) stage(kt + 1, cb ^ 32768); // next-tile loads fly under this kt's MFMA

        const int kq = lane >> 4;
        const int rA = wr * 64 + (lane & 15);
        const int rB = wc * 64 + (lane & 15);
        h16x8 ah[4], al[4], bh[4], bl[4];
#pragma unroll
        for (int mi = 0; mi < 4; ++mi) {
            int r   = rA + mi * 16;
            int off = cb + r * 64 + ((kq ^ ((r >> 1) & 3)) << 4);
            ah[mi] = *(const h16x8*)(lds + off);
            al[mi] = *(const h16x8*)(lds + 8192 + off);
        }
#pragma unroll
        for (int nj = 0; nj < 4; ++nj) {
            int r   = rB + nj * 16;
            int off = cb + r * 64 + ((kq ^ ((r >> 1) & 3)) << 4);
            bh[nj] = *(const h16x8*)(lds + 16384 + off);
            if (isCorr) bl[nj] = *(const h16x8*)(lds + 24576 + off);
        }
        __builtin_amdgcn_s_setprio(1);
#pragma unroll
        for (int mi = 0; mi < 4; ++mi)
#pragma unroll
            for (int nj = 0; nj < 4; ++nj) {
                acc[mi][nj] = __builtin_amdgcn_mfma_f32_16x16x32_f16(ah[mi], bh[nj], acc[mi][nj], 0, 0, 0);
                acc[mi][nj] = __builtin_amdgcn_mfma_f32_16x16x32_f16(al[mi], bh[nj], acc[mi][nj], 0, 0, 0);
                if (isCorr)
                    acc[mi][nj] = __builtin_amdgcn_mfma_f32_16x16x32_f16(ah[mi], bl[nj], acc[mi][nj], 0, 0, 0);
            }
        __builtin_amdgcn_s_setprio(0);
        __syncthreads();       // drains stage(kt+1) + all waves done reading buf[cb]
    }

    const int mBase = i0 + wr * 64;
    const int nBase = j0 + wc * 64;
    if (isCorr) {
        h16* Pb = Ptil + (size_t)b * LROWS * 1024;
        // normal orientation: stats + p_tilde (rows i-range, chunk jt*2+wc)
        {
            const int chunk = jt * 2 + wc;
#pragma unroll
            for (int mi = 0; mi < 4; ++mi)
#pragma unroll
                for (int rg = 0; rg < 4; ++rg) {
                    float v0 = acc[mi][0][rg], v1 = acc[mi][1][rg];
                    float v2 = acc[mi][2][rg], v3 = acc[mi][3][rg];
                    float mx = fmaxf(fmaxf(v0, v1), fmaxf(v2, v3));
#pragma unroll
                    for (int off = 8; off >= 1; off >>= 1) mx = fmaxf(mx, __shfl_xor(mx, off, 64));
                    float e0 = __expf(v0 - mx), e1 = __expf(v1 - mx);
                    float e2 = __expf(v2 - mx), e3 = __expf(v3 - mx);
                    float s = e0 + e1 + e2 + e3;
#pragma unroll
                    for (int off = 8; off >= 1; off >>= 1) s += __shfl_xor(s, off, 64);
                    int row = mBase + mi * 16 + ((lane >> 4) * 4) + rg;
                    if ((lane & 15) == 0)
                        part[((size_t)b * 1024 + row) * 16 + chunk] = make_float2(mx, s);
                    size_t rb = (size_t)row * 1024 + nBase + (lane & 15);
                    Pb[rb]      = (h16)e0;
                    Pb[rb + 16] = (h16)e1;
                    Pb[rb + 32] = (h16)e2;
                    Pb[rb + 48] = (h16)e3;
                }
        }
        if (it != jt) {
            // transposed orientation: rows j-range (n), chunk in i-range
            const int chunk = it * 2 + wr;
#pragma unroll
            for (int nj = 0; nj < 4; ++nj) {
                float mx = -3.0e38f;
#pragma unroll
                for (int mi = 0; mi < 4; ++mi)
#pragma unroll
                    for (int rg = 0; rg < 4; ++rg) mx = fmaxf(mx, acc[mi][nj][rg]);
                mx = fmaxf(mx, __shfl_xor(mx, 16, 64));
                mx = fmaxf(mx, __shfl_xor(mx, 32, 64));
                float s = 0.f;
                h16x4 pt[4];
#pragma unroll
                for (int mi = 0; mi < 4; ++mi)
#pragma unroll
                    for (int rg = 0; rg < 4; ++rg) {
                        float e = __expf(acc[mi][nj][rg] - mx);
                        s += e;
                        pt[mi][rg] = (h16)e;
                    }
                s += __shfl_xor(s, 16, 64);
                s += __shfl_xor(s, 32, 64);
                int n = nBase + nj * 16 + (lane & 15);
                if (lane < 16)
                    part[((size_t)b * 1024 + n) * 16 + chunk] = make_float2(mx, s);
                size_t nb = (size_t)n * 1024 + mBase + ((lane >> 4) * 4);
#pragma unroll
                for (int mi = 0; mi < 4; ++mi)
                    *(h16x4*)(Pb + nb + mi * 16) = pt[mi];
            }
        }
    } else {
        // store t transposed, plain fp16
#pragma unroll
        for (int mi = 0; mi < 4; ++mi)
#pragma unroll
            for (int nj = 0; nj < 4; ++nj) {
                int n  = nBase + nj * 16 + (lane & 15);
                int m0 = mBase + mi * 16 + ((lane >> 4) * 4);
                h16x4 hv;
#pragma unroll
                for (int rg = 0; rg < 4; ++rg) hv[rg] = (h16)acc[mi][nj][rg];
                size_t off = ((size_t)b * 256 + n) * 1024 + m0;  // tT[b][g][l]
                *(h16x4*)(Th + off) = hv;
            }
    }
}

// ---------- PV: p = p_tilde * exp(m_chunk - M)/S; At=p (fp32); Node = relu(x + p·t) ----------
// M-tile 32, N full 256 (4 waves x 64-col quadrants), K=1024, Kt=64. 512 blocks, 4/CU.
// Grid aligned with gemm_ct: batch b on XCD b%8 (id&7), bit3 selects b vs b+8.
__global__ __launch_bounds__(256, 4) void gemm_pv(
    const h16* __restrict__ Ptil, const float2* __restrict__ part,
    float* __restrict__ At,
    const h16* __restrict__ Th,
    h16* __restrict__ Xh, h16* __restrict__ Xl,
    float* __restrict__ NodeOut, float* __restrict__ OutBase, int last) {
    const int id   = blockIdx.x;
    const int b    = (id & 7) | (((id >> 3) & 1) << 3);   // XCD b%8, matching gemm_ct
    const int mt   = id >> 4;                             // 0..31
    const int i0   = mt * 32;
    const int t    = threadIdx.x;
    const int lane = t & 63, wid = t >> 6;
    const int wc   = wid;                          // n-quadrant 0..3

    __shared__ alignas(16) char lds[38912];
    // A [32][64]h16 @0 (4K, swizzled) | B [256][64]h16 @4096 (32K) | sc [32][16]f32 @36864 (2K)
    float* sc = (float*)(lds + 36864);

    // stats prologue: per-row M,S then per-(row,chunk) scale
    if (t < 32) {
        const float2* pp = part + ((size_t)b * 1024 + i0 + t) * 16;
        float2 v[16];
        float M = -3.0e38f;
#pragma unroll
        for (int c = 0; c < 16; ++c) { v[c] = pp[c]; M = fmaxf(M, v[c].x); }
        float S = 0.f;
#pragma unroll
        for (int c = 0; c < 16; ++c) S += v[c].y * __expf(v[c].x - M);
        float inv = 1.0f / S;
#pragma unroll
        for (int c = 0; c < 16; ++c) sc[t * 16 + c] = __expf(v[c].x - M) * inv;
    }
    __syncthreads();

    const h16* Prow = Ptil + ((size_t)b * LROWS + i0) * 1024;
    float* Arow = At + ((size_t)b * LROWS + i0) * 1024;
    const size_t tbase = (size_t)b * 256 * 1024;

    const int ar = t >> 3;       // 0..31 (A row / B row-group)
    const int ac = t & 7;        // 8-col group

    f32x4 acc[2][4];
#pragma unroll
    for (int i = 0; i < 2; ++i)
#pragma unroll
        for (int j = 0; j < 4; ++j) acc[i][j] = (f32x4){0.f, 0.f, 0.f, 0.f};

    for (int kt = 0; kt < 16; ++kt) {
        // A: p_tilde fp16 load + per-chunk scale (global/LDS-sc reads — before barrier is fine)
        h16x8 pt = *(const h16x8*)(Prow + (size_t)ar * 1024 + kt * 64 + ac * 8);
        float s  = sc[ar * 16 + kt];
        __syncthreads();         // prior MFMA done reading LDS A/B

        // B: async global->LDS, pre-swizzled per-lane source, linear dest
#pragma unroll
        for (int itr = 0; itr < 8; ++itr) {
            int g = itr * 32 + ar;
            size_t so = tbase + (size_t)g * 1024 + kt * 64 + ((ac ^ (g & 7)) << 3);
            char* d = lds + 4096 + itr * 4096 + wid * 1024;
            gl_lds16(Th + so, d);
        }

        // normalize: write fp32 attn to d_out, stage fp16 product to LDS
        f32x4 plo, phi;
#pragma unroll
        for (int e = 0; e < 4; ++e) plo[e] = (float)pt[e] * s;
#pragma unroll
        for (int e = 0; e < 4; ++e) phi[e] = (float)pt[4 + e] * s;
        *(f32x4*)(Arow + (size_t)ar * 1024 + kt * 64 + ac * 8)     = plo;
        *(f32x4*)(Arow + (size_t)ar * 1024 + kt * 64 + ac * 8 + 4) = phi;
        h16x8 a16;
#pragma unroll
        for (int e = 0; e < 4; ++e) { a16[e] = (h16)plo[e]; a16[4 + e] = (h16)phi[e]; }
        *(h16x8*)(lds + ar * 128 + ((ac ^ (ar & 7)) << 4)) = a16;
        __syncthreads();         // drains ds_writes + global_load_lds

        const int kq = lane >> 4;
        __builtin_amdgcn_s_setprio(1);
#pragma unroll
        for (int s2 = 0; s2 < 2; ++s2) {
            h16x8 ah[2], bh[4];
#pragma unroll
            for (int mi = 0; mi < 2; ++mi) {
                int r = mi * 16 + (lane & 15);
                ah[mi] = *(const h16x8*)(lds + r * 128 + (((s2 * 4 + kq) ^ (r & 7)) << 4));
            }
#pragma unroll
            for (int nf = 0; nf < 4; ++nf) {
                int g = wc * 64 + nf * 16 + (lane & 15);
                bh[nf] = *(const h16x8*)(lds + 4096 + g * 128 + (((s2 * 4 + kq) ^ (g & 7)) << 4));
            }
#pragma unroll
            for (int mi = 0; mi < 2; ++mi)
#pragma unroll
                for (int nf = 0; nf < 4; ++nf)
                    acc[mi][nf] = __builtin_amdgcn_mfma_f32_16x16x32_f16(ah[mi], bh[nf], acc[mi][nf], 0, 0, 0);
        }
        __builtin_amdgcn_s_setprio(0);
    }

    // epilogue: residual + relu, update x hi/lo, write node (+final slices)
#pragma unroll
    for (int mi = 0; mi < 2; ++mi)
#pragma unroll
        for (int nf = 0; nf < 4; ++nf) {
            int n = wc * 64 + nf * 16 + (lane & 15);
#pragma unroll
            for (int rg = 0; rg < 4; ++rg) {
                int m = i0 + mi * 16 + ((lane >> 4) * 4) + rg;
                size_t off = ((size_t)b * LROWS + m) * FDIM + n;
                float res = (float)Xh[off] + (float)Xl[off];
                float y   = res + acc[mi][nf][rg];
                y = y > 0.f ? y : 0.f;
                NodeOut[off] = y;
                h16 hh, ll; split2(y, hh, ll);
                Xh[off] = hh; Xl[off] = ll;
                if (last) {
                    float* dst = (m < 256)
                        ? OutBase + OFF_TGT + ((size_t)b << 16) + ((size_t)m << 8) + n
                        : OutBase + OFF_CLM + (size_t)b * 196608 + ((size_t)(m - 256) << 8) + n;
                    *dst = y;
                }
            }
        }
}

// ---------- host ----------
extern "C" void kernel_launch(void* const* d_in, const int* in_sizes, int n_in,
                              void* d_out, int out_size, void* d_ws, size_t ws_size,
                              hipStream_t stream) {
    (void)in_sizes; (void)n_in; (void)out_size; (void)ws_size;
    const float* tgt = (const float*)d_in[0];
    const float* clm = (const float*)d_in[1];
    // d_in[2] = batch_adj: unused by the reference computation
    const float* W   = (const float*)d_in[3];
    float* out = (float*)d_out;
    char*  ws  = (char*)d_ws;

    h16* xh = (h16*)(ws);                            // 8 MB
    h16* xl = (h16*)(ws + (8ull << 20));             // 8 MB
    h16* th = (h16*)(ws + (16ull << 20));            // 8 MB
    h16* wh = (h16*)(ws + (24ull << 20));            // 384 KB
    float2* part = (float2*)(ws + (25ull << 20));    // 2 MB
    h16* ptil = (h16*)(ws + (27ull << 20));          // 32 MB: p_tilde fp16 [16][1024][1024]

    convert_all<<<4288, 256, 0, stream>>>(tgt, clm, W, xh, xl, wh);

    for (int L = 0; L < 3; ++L) {
        float* at = out + OFF_AT + (size_t)L * 16777216ull;
        float* nr = out + OFF_NR + (size_t)L * 4194304ull;
        gemm_ct<<<832, 256, 0, stream>>>(xh, xl, wh + (size_t)L * 65536, ptil, part, th);
        gemm_pv<<<512, 256, 0, stream>>>(ptil, part, at, th, xh, xl, nr, out, L == 2);
    }
}

// Round 12
// 209.816 us; speedup vs baseline: 1.0950x; 1.0950x over previous
//
#include <hip/hip_runtime.h>

// ---------- types ----------
typedef _Float16 h16;
typedef _Float16 h16x8 __attribute__((ext_vector_type(8)));
typedef _Float16 h16x4 __attribute__((ext_vector_type(4)));
typedef float    f32x4 __attribute__((ext_vector_type(4)));

#define NBATCH 16
#define LROWS  1024
#define FDIM   256

// d_out element offsets (fp32 elements)
#define OFF_TGT 0ull
#define OFF_CLM 1048576ull
#define OFF_NR  4194304ull     // + layer*4194304
#define OFF_AT  16777216ull    // + layer*16777216

__device__ __forceinline__ void split2(float x, h16& h, h16& l) {
    h = (h16)x;
    l = (h16)(x - (float)h);
}

// global_load_lds width-16 helper (dest = wave-uniform base + lane*16)
typedef const __attribute__((address_space(1))) void gvoid;
typedef __attribute__((address_space(3))) void lvoid;
__device__ __forceinline__ void gl_lds16(const void* g, void* l) {
    __builtin_amdgcn_global_load_lds((gvoid*)g, (lvoid*)l, 16, 0, 0);
}

// upper-triangle tile enumeration (36 pairs, it <= jt, 8x8 tiles)
__device__ const unsigned char TRI_I[36] = {
    0,0,0,0,0,0,0,0, 1,1,1,1,1,1,1, 2,2,2,2,2,2, 3,3,3,3,3, 4,4,4,4, 5,5,5, 6,6, 7};
__device__ const unsigned char TRI_J[36] = {
    0,1,2,3,4,5,6,7, 1,2,3,4,5,6,7, 2,3,4,5,6,7, 3,4,5,6,7, 4,5,6,7, 5,6,7, 6,7, 7};

// ---------- init: concat(target,claim) -> x hi/lo fp16 ; W -> hi fp16 ----------
// XCD-aligned: batch b's conversion runs on XCD b%8 (same as gemm_ct consumer).
__global__ __launch_bounds__(256) void convert_all(const float* __restrict__ tgt,
                                                   const float* __restrict__ clm,
                                                   const float* __restrict__ W,
                                                   h16* __restrict__ xh, h16* __restrict__ xl,
                                                   h16* __restrict__ wh) {
    int bid = blockIdx.x;
    if (bid < 4096) {
        int b, i;
        if (bid < 2048) { b = bid & 7;       i = bid >> 3; }
        else            { b = 8 + (bid & 7); i = (bid - 2048) >> 3; }
        size_t e = ((size_t)b << 18) + (size_t)i * 1024 + (size_t)threadIdx.x * 4;
        int rf = (int)(e & 262143);
        int r  = rf >> 8, f = rf & 255;
        const float* src = (r < 256)
            ? tgt + ((size_t)b << 16) + ((size_t)r << 8) + f
            : clm + (size_t)b * 196608 + ((size_t)(r - 256) << 8) + f;
        f32x4 v = *(const f32x4*)src;
        h16x4 hv, lv;
#pragma unroll
        for (int j = 0; j < 4; ++j) { h16 hh, ll; split2(v[j], hh, ll); hv[j] = hh; lv[j] = ll; }
        *(h16x4*)(xh + e) = hv;
        *(h16x4*)(xl + e) = lv;
    } else {
        size_t e = ((size_t)(bid - 4096) * 256 + threadIdx.x) * 4;
        f32x4 v = *(const f32x4*)(W + e);
        h16x4 hv;
#pragma unroll
        for (int j = 0; j < 4; ++j) hv[j] = (h16)v[j];
        *(h16x4*)(wh + e) = hv;
    }
}

// ---------- fused corr(symmetric)+trans, BK=32, 32KB LDS, 3/CU ----------
// XCD-aware grid: batch = bid & 15, unit = bid >> 4 (all units of a batch on one XCD).
// corr (u<36): 3-term split logits; p_tilde = exp(v - m_chunk) fp16 for BOTH
//   orientations + per-(row,64col-chunk) (max,sumexp) partials for both orientations.
//   Transposed p_tilde store goes through an LDS bounce for dense 1KB stores.
// trans (u>=36): 2-term (ah+al)·Wh; store transposed fp16 tT[b][g][l].
__global__ __launch_bounds__(256, 3) void gemm_ct(
    const h16* __restrict__ Xh, const h16* __restrict__ Xl,
    const h16* __restrict__ Wh,
    h16* __restrict__ Ptil, float2* __restrict__ part,
    h16* __restrict__ Th) {
    const int b = blockIdx.x & 15;
    const int u = blockIdx.x >> 4;
    const bool isCorr = u < 36;
    int it, jt;
    if (isCorr) { it = TRI_I[u]; jt = TRI_J[u]; }
    else        { int v = u - 36; it = v >> 1; jt = v & 1; }
    const int i0 = it * 128;
    const int j0 = jt * 128;
    const int t  = threadIdx.x;
    const int lane = t & 63, wid = t >> 6;
    const int wr = wid >> 1, wc = wid & 1;

    __shared__ alignas(16) char lds[32768];  // Ah@0 | Al@8K | Bh@16K | Bl@24K, each [128][32]h16
                                             // epilogue reuse: [128 col][128 row] h16 (granule-XOR)

    const size_t arow = ((size_t)b * LROWS + i0) * 256;
    const h16* bHp; const h16* bLp; size_t brow;
    if (isCorr) { bHp = Xh; bLp = Xl; brow = ((size_t)b * LROWS + j0) * 256; }
    else        { bHp = Wh; bLp = Xl; brow = (size_t)j0 * 256; }   // bLp unused for trans

    f32x4 acc[4][4];
#pragma unroll
    for (int i = 0; i < 4; ++i)
#pragma unroll
        for (int j = 0; j < 4; ++j) acc[i][j] = (f32x4){0.f, 0.f, 0.f, 0.f};

    const int grow = t >> 2;   // 0..63
    const int gq   = t & 3;    // 16B chunk within 64B row

    for (int kt = 0; kt < 8; ++kt) {
        __syncthreads();       // prior MFMA done reading LDS
#pragma unroll
        for (int p = 0; p < 2; ++p) {
            int r = p * 64 + grow;
            size_t so = (size_t)r * 256 + kt * 32 + ((gq ^ ((r >> 1) & 3)) << 3);
            char* d = lds + p * 4096 + wid * 1024;
            gl_lds16(Xh + arow + so, d);
            gl_lds16(Xl + arow + so, d + 8192);
            gl_lds16(bHp + brow + so, d + 16384);
            if (isCorr) gl_lds16(bLp + brow + so, d + 24576);
        }
        __syncthreads();       // drains global_load_lds

        const int kq = lane >> 4;
        const int rA = wr * 64 + (lane & 15);
        const int rB = wc * 64 + (lane & 15);
        h16x8 ah[4], al[4], bh[4], bl[4];
#pragma unroll
        for (int mi = 0; mi < 4; ++mi) {
            int r   = rA + mi * 16;
            int off = r * 64 + ((kq ^ ((r >> 1) & 3)) << 4);
            ah[mi] = *(const h16x8*)(lds + off);
            al[mi] = *(const h16x8*)(lds + 8192 + off);
        }
#pragma unroll
        for (int nj = 0; nj < 4; ++nj) {
            int r   = rB + nj * 16;
            int off = r * 64 + ((kq ^ ((r >> 1) & 3)) << 4);
            bh[nj] = *(const h16x8*)(lds + 16384 + off);
            if (isCorr) bl[nj] = *(const h16x8*)(lds + 24576 + off);
        }
        __builtin_amdgcn_s_setprio(1);
#pragma unroll
        for (int mi = 0; mi < 4; ++mi)
#pragma unroll
            for (int nj = 0; nj < 4; ++nj) {
                acc[mi][nj] = __builtin_amdgcn_mfma_f32_16x16x32_f16(ah[mi], bh[nj], acc[mi][nj], 0, 0, 0);
                acc[mi][nj] = __builtin_amdgcn_mfma_f32_16x16x32_f16(al[mi], bh[nj], acc[mi][nj], 0, 0, 0);
                if (isCorr)
                    acc[mi][nj] = __builtin_amdgcn_mfma_f32_16x16x32_f16(ah[mi], bl[nj], acc[mi][nj], 0, 0, 0);
            }
        __builtin_amdgcn_s_setprio(0);
    }

    const int mBase = i0 + wr * 64;
    const int nBase = j0 + wc * 64;
    if (isCorr) {
        h16* Pb = Ptil + (size_t)b * LROWS * 1024;
        // normal orientation: stats + p_tilde (rows i-range, chunk jt*2+wc)
        {
            const int chunk = jt * 2 + wc;
#pragma unroll
            for (int mi = 0; mi < 4; ++mi)
#pragma unroll
                for (int rg = 0; rg < 4; ++rg) {
                    float v0 = acc[mi][0][rg], v1 = acc[mi][1][rg];
                    float v2 = acc[mi][2][rg], v3 = acc[mi][3][rg];
                    float mx = fmaxf(fmaxf(v0, v1), fmaxf(v2, v3));
#pragma unroll
                    for (int off = 8; off >= 1; off >>= 1) mx = fmaxf(mx, __shfl_xor(mx, off, 64));
                    float e0 = __expf(v0 - mx), e1 = __expf(v1 - mx);
                    float e2 = __expf(v2 - mx), e3 = __expf(v3 - mx);
                    float s = e0 + e1 + e2 + e3;
#pragma unroll
                    for (int off = 8; off >= 1; off >>= 1) s += __shfl_xor(s, off, 64);
                    int row = mBase + mi * 16 + ((lane >> 4) * 4) + rg;
                    if ((lane & 15) == 0)
                        part[((size_t)b * 1024 + row) * 16 + chunk] = make_float2(mx, s);
                    size_t rb = (size_t)row * 1024 + nBase + (lane & 15);
                    Pb[rb]      = (h16)e0;
                    Pb[rb + 16] = (h16)e1;
                    Pb[rb + 32] = (h16)e2;
                    Pb[rb + 48] = (h16)e3;
                }
        }
        if (it != jt) {
            __syncthreads();   // all waves done with K-loop LDS reads; reuse LDS for bounce
            // transposed orientation: rows j-range (n), chunk in i-range
            const int chunk = it * 2 + wr;
            const int cl0 = wc * 64 + (lane & 15);                 // tile-local col base
            const int r40 = wr * 64 + ((lane >> 4) << 2);          // tile-local 4-row granule base
#pragma unroll
            for (int nj = 0; nj < 4; ++nj) {
                float mx = -3.0e38f;
#pragma unroll
                for (int mi = 0; mi < 4; ++mi)
#pragma unroll
                    for (int rg = 0; rg < 4; ++rg) mx = fmaxf(mx, acc[mi][nj][rg]);
                mx = fmaxf(mx, __shfl_xor(mx, 16, 64));
                mx = fmaxf(mx, __shfl_xor(mx, 32, 64));
                float s = 0.f;
                h16x4 pt[4];
#pragma unroll
                for (int mi = 0; mi < 4; ++mi)
#pragma unroll
                    for (int rg = 0; rg < 4; ++rg) {
                        float e = __expf(acc[mi][nj][rg] - mx);
                        s += e;
                        pt[mi][rg] = (h16)e;
                    }
                s += __shfl_xor(s, 16, 64);
                s += __shfl_xor(s, 32, 64);
                int n = nBase + nj * 16 + (lane & 15);
                if (lane < 16)
                    part[((size_t)b * 1024 + n) * 16 + chunk] = make_float2(mx, s);
                // stage granules col-major into LDS: [col][row], granule XOR by col
                const int cl = cl0 + nj * 16;
#pragma unroll
                for (int mi = 0; mi < 4; ++mi) {
                    int r4 = r40 + mi * 16;
                    *(h16x4*)(lds + cl * 256 + (((r4 ^ ((cl & 7) << 2))) << 1)) = pt[mi];
                }
            }
            __syncthreads();
            // dense transposed copy-out: per wave-instr 4 cols x 256B contiguous (1KB)
#pragma unroll
            for (int i8 = 0; i8 < 8; ++i8) {
                int cl = wid * 32 + i8 * 4 + (lane >> 4);          // tile-local col 0..127
                int R  = (lane & 15) * 8;                          // row base 0..120
                int k4 = (cl & 7) << 2;
                h16x4 v0 = *(const h16x4*)(lds + cl * 256 + (((R    ) ^ k4) << 1));
                h16x4 v1 = *(const h16x4*)(lds + cl * 256 + (((R + 4) ^ k4) << 1));
                h16x8 vv;
                vv[0] = v0[0]; vv[1] = v0[1]; vv[2] = v0[2]; vv[3] = v0[3];
                vv[4] = v1[0]; vv[5] = v1[1]; vv[6] = v1[2]; vv[7] = v1[3];
                *(h16x8*)(Pb + (size_t)(j0 + cl) * 1024 + i0 + R) = vv;
            }
        }
    } else {
        // store t transposed, plain fp16
#pragma unroll
        for (int mi = 0; mi < 4; ++mi)
#pragma unroll
            for (int nj = 0; nj < 4; ++nj) {
                int n  = nBase + nj * 16 + (lane & 15);
                int m0 = mBase + mi * 16 + ((lane >> 4) * 4);
                h16x4 hv;
#pragma unroll
                for (int rg = 0; rg < 4; ++rg) hv[rg] = (h16)acc[mi][nj][rg];
                size_t off = ((size_t)b * 256 + n) * 1024 + m0;  // tT[b][g][l]
                *(h16x4*)(Th + off) = hv;
            }
    }
}

// ---------- PV: p = p_tilde * exp(m_chunk - M)/S; At=p (fp32); Node = relu(x + p·t) ----------
// M-tile 32, N full 256 (4 waves x 64-col quadrants), K=1024, Kt=64. 512 blocks, 4/CU.
// Grid aligned with gemm_ct: batch b on XCD b%8 (id&7), bit3 selects b vs b+8.
__global__ __launch_bounds__(256, 4) void gemm_pv(
    const h16* __restrict__ Ptil, const float2* __restrict__ part,
    float* __restrict__ At,
    const h16* __restrict__ Th,
    h16* __restrict__ Xh, h16* __restrict__ Xl,
    float* __restrict__ NodeOut, float* __restrict__ OutBase, int last) {
    const int id   = blockIdx.x;
    const int b    = (id & 7) | (((id >> 3) & 1) << 3);   // XCD b%8, matching gemm_ct
    const int mt   = id >> 4;                             // 0..31
    const int i0   = mt * 32;
    const int t    = threadIdx.x;
    const int lane = t & 63, wid = t >> 6;
    const int wc   = wid;                          // n-quadrant 0..3

    __shared__ alignas(16) char lds[38912];
    // A [32][64]h16 @0 (4K, swizzled) | B [256][64]h16 @4096 (32K) | sc [32][16]f32 @36864 (2K)
    float* sc = (float*)(lds + 36864);

    // stats prologue: per-row M,S then per-(row,chunk) scale
    if (t < 32) {
        const float2* pp = part + ((size_t)b * 1024 + i0 + t) * 16;
        float2 v[16];
        float M = -3.0e38f;
#pragma unroll
        for (int c = 0; c < 16; ++c) { v[c] = pp[c]; M = fmaxf(M, v[c].x); }
        float S = 0.f;
#pragma unroll
        for (int c = 0; c < 16; ++c) S += v[c].y * __expf(v[c].x - M);
        float inv = 1.0f / S;
#pragma unroll
        for (int c = 0; c < 16; ++c) sc[t * 16 + c] = __expf(v[c].x - M) * inv;
    }
    __syncthreads();

    const h16* Prow = Ptil + ((size_t)b * LROWS + i0) * 1024;
    float* Arow = At + ((size_t)b * LROWS + i0) * 1024;
    const size_t tbase = (size_t)b * 256 * 1024;

    const int ar = t >> 3;       // 0..31 (A row / B row-group)
    const int ac = t & 7;        // 8-col group

    f32x4 acc[2][4];
#pragma unroll
    for (int i = 0; i < 2; ++i)
#pragma unroll
        for (int j = 0; j < 4; ++j) acc[i][j] = (f32x4){0.f, 0.f, 0.f, 0.f};

    for (int kt = 0; kt < 16; ++kt) {
        // A: p_tilde fp16 load + per-chunk scale (global/LDS-sc reads — before barrier is fine)
        h16x8 pt = *(const h16x8*)(Prow + (size_t)ar * 1024 + kt * 64 + ac * 8);
        float s  = sc[ar * 16 + kt];
        __syncthreads();         // prior MFMA done reading LDS A/B

        // B: async global->LDS, pre-swizzled per-lane source, linear dest
#pragma unroll
        for (int itr = 0; itr < 8; ++itr) {
            int g = itr * 32 + ar;
            size_t so = tbase + (size_t)g * 1024 + kt * 64 + ((ac ^ (g & 7)) << 3);
            char* d = lds + 4096 + itr * 4096 + wid * 1024;
            gl_lds16(Th + so, d);
        }

        // normalize: write fp32 attn to d_out, stage fp16 product to LDS
        f32x4 plo, phi;
#pragma unroll
        for (int e = 0; e < 4; ++e) plo[e] = (float)pt[e] * s;
#pragma unroll
        for (int e = 0; e < 4; ++e) phi[e] = (float)pt[4 + e] * s;
        *(f32x4*)(Arow + (size_t)ar * 1024 + kt * 64 + ac * 8)     = plo;
        *(f32x4*)(Arow + (size_t)ar * 1024 + kt * 64 + ac * 8 + 4) = phi;
        h16x8 a16;
#pragma unroll
        for (int e = 0; e < 4; ++e) { a16[e] = (h16)plo[e]; a16[4 + e] = (h16)phi[e]; }
        *(h16x8*)(lds + ar * 128 + ((ac ^ (ar & 7)) << 4)) = a16;
        __syncthreads();         // drains ds_writes + global_load_lds

        const int kq = lane >> 4;
        __builtin_amdgcn_s_setprio(1);
#pragma unroll
        for (int s2 = 0; s2 < 2; ++s2) {
            h16x8 ah[2], bh[4];
#pragma unroll
            for (int mi = 0; mi < 2; ++mi) {
                int r = mi * 16 + (lane & 15);
                ah[mi] = *(const h16x8*)(lds + r * 128 + (((s2 * 4 + kq) ^ (r & 7)) << 4));
            }
#pragma unroll
            for (int nf = 0; nf < 4; ++nf) {
                int g = wc * 64 + nf * 16 + (lane & 15);
                bh[nf] = *(const h16x8*)(lds + 4096 + g * 128 + (((s2 * 4 + kq) ^ (g & 7)) << 4));
            }
#pragma unroll
            for (int mi = 0; mi < 2; ++mi)
#pragma unroll
                for (int nf = 0; nf < 4; ++nf)
                    acc[mi][nf] = __builtin_amdgcn_mfma_f32_16x16x32_f16(ah[mi], bh[nf], acc[mi][nf], 0, 0, 0);
        }
        __builtin_amdgcn_s_setprio(0);
    }

    // epilogue: residual + relu, update x hi/lo, write node (+final slices)
#pragma unroll
    for (int mi = 0; mi < 2; ++mi)
#pragma unroll
        for (int nf = 0; nf < 4; ++nf) {
            int n = wc * 64 + nf * 16 + (lane & 15);
#pragma unroll
            for (int rg = 0; rg < 4; ++rg) {
                int m = i0 + mi * 16 + ((lane >> 4) * 4) + rg;
                size_t off = ((size_t)b * LROWS + m) * FDIM + n;
                float res = (float)Xh[off] + (float)Xl[off];
                float y   = res + acc[mi][nf][rg];
                y = y > 0.f ? y : 0.f;
                NodeOut[off] = y;
                h16 hh, ll; split2(y, hh, ll);
                Xh[off] = hh; Xl[off] = ll;
                if (last) {
                    float* dst = (m < 256)
                        ? OutBase + OFF_TGT + ((size_t)b << 16) + ((size_t)m << 8) + n
                        : OutBase + OFF_CLM + (size_t)b * 196608 + ((size_t)(m - 256) << 8) + n;
                    *dst = y;
                }
            }
        }
}

// ---------- host ----------
extern "C" void kernel_launch(void* const* d_in, const int* in_sizes, int n_in,
                              void* d_out, int out_size, void* d_ws, size_t ws_size,
                              hipStream_t stream) {
    (void)in_sizes; (void)n_in; (void)out_size; (void)ws_size;
    const float* tgt = (const float*)d_in[0];
    const float* clm = (const float*)d_in[1];
    // d_in[2] = batch_adj: unused by the reference computation
    const float* W   = (const float*)d_in[3];
    float* out = (float*)d_out;
    char*  ws  = (char*)d_ws;

    h16* xh = (h16*)(ws);                            // 8 MB
    h16* xl = (h16*)(ws + (8ull << 20));             // 8 MB
    h16* th = (h16*)(ws + (16ull << 20));            // 8 MB
    h16* wh = (h16*)(ws + (24ull << 20));            // 384 KB
    float2* part = (float2*)(ws + (25ull << 20));    // 2 MB
    h16* ptil = (h16*)(ws + (27ull << 20));          // 32 MB: p_tilde fp16 [16][1024][1024]

    convert_all<<<4288, 256, 0, stream>>>(tgt, clm, W, xh, xl, wh);

    for (int L = 0; L < 3; ++L) {
        float* at = out + OFF_AT + (size_t)L * 16777216ull;
        float* nr = out + OFF_NR + (size_t)L * 4194304ull;
        gemm_ct<<<832, 256, 0, stream>>>(xh, xl, wh + (size_t)L * 65536, ptil, part, th);
        gemm_pv<<<512, 256, 0, stream>>>(ptil, part, at, th, xh, xl, nr, out, L == 2);
    }
}